// Round 2
// baseline (3193.202 us; speedup 1.0000x reference)
//
#include <hip/hip_runtime.h>
#include <hip/hip_cooperative_groups.h>
#include <math.h>

namespace cg = cooperative_groups;

#define N 1024
#define F 4096
#define NLAYERS 24
#define VOCAB 50277
#define GRID 256
#define BLOCK 512   // 8 waves per block, 1 block per CU

__device__ __forceinline__ float wred(float v) {
#pragma unroll
  for (int o = 32; o > 0; o >>= 1) v += __shfl_down(v, o, 64);
  return v;
}

__device__ __forceinline__ float sigmoidf(float x) { return 1.f / (1.f + expf(-x)); }

// partial dot: one wave over `cols` columns (cols multiple of 256)
__device__ __forceinline__ float wave_pdot(const float* __restrict__ wrow,
                                           const float* __restrict__ vec,
                                           int cols, int lane) {
  float acc = 0.f;
  for (int c = lane * 4; c < cols; c += 256) {
    float4 wv = *(const float4*)(wrow + c);
    float4 vv = *(const float4*)(vec + c);
    acc = fmaf(wv.x, vv.x, fmaf(wv.y, vv.y, fmaf(wv.z, vv.z, fmaf(wv.w, vv.w, acc))));
  }
  return wred(acc);
}

// LayerNorm of 1024-vector, 512 threads, one float2 per thread.
__device__ __forceinline__ float2 block_ln2(float2 xv, const float* __restrict__ w,
                                            const float* __restrict__ b, float* s_red) {
  int tid = threadIdx.x;
  __syncthreads();  // protect s_red reuse across calls
  float s = xv.x + xv.y;
  float sq = xv.x * xv.x + xv.y * xv.y;
#pragma unroll
  for (int o = 32; o > 0; o >>= 1) {
    s += __shfl_down(s, o, 64);
    sq += __shfl_down(sq, o, 64);
  }
  int wid = tid >> 6;
  if ((tid & 63) == 0) { s_red[wid] = s; s_red[8 + wid] = sq; }
  __syncthreads();
  if (tid == 0) {
    float ts = 0.f, tq = 0.f;
#pragma unroll
    for (int i = 0; i < 8; i++) { ts += s_red[i]; tq += s_red[8 + i]; }
    float mu = ts * (1.0f / N);
    float var = tq * (1.0f / N) - mu * mu;
    s_red[0] = mu;
    s_red[1] = rsqrtf(var + 1e-5f);
  }
  __syncthreads();
  float mu = s_red[0], rstd = s_red[1];
  float2 wv = ((const float2*)w)[tid];
  float2 bv = ((const float2*)b)[tid];
  float2 y;
  y.x = (xv.x - mu) * rstd * wv.x + bv.x;
  y.y = (xv.y - mu) * rstd * wv.y + bv.y;
  return y;
}

__device__ __forceinline__ float2 mix2(float2 a, float2 s, float2 m) {
  float2 r;
  r.x = a.x * m.x + s.x * (1.f - m.x);
  r.y = a.y * m.y + s.y * (1.f - m.y);
  return r;
}

__device__ __forceinline__ void wkv1(float k, float v, float r, float aa, float bb,
                                     float pp, float tf, float td, float& rab,
                                     float& naa, float& nbb, float& npp) {
  float ww = tf + k;
  float q = fmaxf(pp, ww);
  float e1 = expf(pp - q);
  float e2 = expf(ww - q);
  float a = e1 * aa + e2 * v;
  float b = e1 * bb + e2;
  rab = r * a / b;
  float ww2 = pp + td;
  float q2 = fmaxf(ww2, k);
  float f1 = expf(ww2 - q2);
  float f2 = expf(k - q2);
  naa = f1 * aa + f2 * v;
  nbb = f1 * bb + f2;
  npp = q2;
}

__global__ __launch_bounds__(BLOCK, 1) void k_rwkv(
    const int* __restrict__ ctx, const float* __restrict__ state,
    const float* __restrict__ emb, const float* __restrict__ ln0w,
    const float* __restrict__ ln0b, const float* __restrict__ ln1w,
    const float* __restrict__ ln1b, const float* __restrict__ amk,
    const float* __restrict__ amv, const float* __restrict__ amr,
    const float* __restrict__ tf, const float* __restrict__ td,
    const float* __restrict__ kw, const float* __restrict__ vw,
    const float* __restrict__ rw, const float* __restrict__ ow,
    const float* __restrict__ ln2w, const float* __restrict__ ln2b,
    const float* __restrict__ fmk, const float* __restrict__ fmr,
    const float* __restrict__ fkw, const float* __restrict__ fvw,
    const float* __restrict__ frw, const float* __restrict__ lnoutw,
    const float* __restrict__ lnoutb, const float* __restrict__ head,
    float* __restrict__ out, float* __restrict__ ws) {
  cg::grid_group grid = cg::this_grid();
  __shared__ float s_buf[4096];   // 16 KB staging (mix vectors / rab / kk / xf)
  __shared__ float s_red[16];
  __shared__ float s_part[40];

  const int tid = threadIdx.x;
  const int lane = tid & 63;
  const int wid = tid >> 6;
  const int blk = blockIdx.x;

  float* logits = out;
  float* st_out = out + VOCAB;
  float* xg = ws;                 // N
  float* kbuf = ws + N;           // N
  float* vbuf = ws + 2 * N;       // N
  float* rbuf = ws + 3 * N;       // N
  float* sxbuf = ws + 4 * N;      // N
  float* kkbuf = ws + 5 * N;      // F
  float* r2buf = ws + 5 * N + F;  // N

  // ---- embed + ln0 (redundant per block; block 0 writes) ----
  {
    int t_last = ctx[1], t_prev = ctx[0];
    float2 e1 = ((const float2*)(emb + (size_t)t_last * N))[tid];
    float2 e0 = ((const float2*)(emb + (size_t)t_prev * N))[tid];
    float2 xv;
    xv.x = (e1.x * 4.f + e0.x) * 0.2f;
    xv.y = (e1.y * 4.f + e0.y) * 0.2f;
    float2 y = block_ln2(xv, ln0w, ln0b, s_red);
    if (blk == 0) ((float2*)xg)[tid] = y;
  }
  grid.sync();

  for (int l = 0; l < NLAYERS; ++l) {
    const size_t nn = (size_t)N * N;
    const float* st_l = state + (size_t)l * 5 * N;
    float* sto = st_out + (size_t)l * 5 * N;
    const float* kw_l = kw + l * nn;
    const float* vw_l = vw + l * nn;
    const float* rw_l = rw + l * nn;
    const float* ow_l = ow + l * nn;
    const float* fkw_l = fkw + (size_t)l * F * N;
    const float* fvw_l = fvw + (size_t)l * N * F;
    const float* frw_l = frw + l * nn;

    // ======== Stage A: xl = LN(x); k,v,r matvecs (3072 rows) ========
    {
      float2 xv = ((const float2*)xg)[tid];
      float2 xl = block_ln2(xv, ln1w + l * N, ln1b + l * N, s_red);
      if (blk == 0) ((float2*)(sto + N))[tid] = xl;
      float2 sv = ((const float2*)(st_l + N))[tid];
      ((float2*)(s_buf + 0))[tid]    = mix2(xl, sv, ((const float2*)(amk + l * N))[tid]);
      ((float2*)(s_buf + 1024))[tid] = mix2(xl, sv, ((const float2*)(amv + l * N))[tid]);
      ((float2*)(s_buf + 2048))[tid] = mix2(xl, sv, ((const float2*)(amr + l * N))[tid]);
      __syncthreads();
      for (int h = wid; h < 24; h += 8) {
        int i = h >> 1, half = h & 1;
        int gr = blk * 12 + i;
        int m = gr >> 10, rr = gr & (N - 1);
        const float* wm = (m == 0 ? kw_l : (m == 1 ? vw_l : rw_l));
        float p = wave_pdot(wm + (size_t)rr * N + half * 512,
                            s_buf + m * 1024 + half * 512, 512, lane);
        if (lane == 0) s_part[h] = p;
      }
      __syncthreads();
      if (tid < 12) {
        int gr = blk * 12 + tid;
        int m = gr >> 10, rr = gr & (N - 1);
        float val = s_part[2 * tid] + s_part[2 * tid + 1];
        if (m == 0) kbuf[rr] = val;
        else if (m == 1) vbuf[rr] = val;
        else rbuf[rr] = sigmoidf(val);
      }
    }
    grid.sync();

    // ======== Stage B: WKV (redundant) + ow matvec (1024 rows) ========
    {
      float2 k2 = ((const float2*)kbuf)[tid];
      float2 v2 = ((const float2*)vbuf)[tid];
      float2 r2 = ((const float2*)rbuf)[tid];
      float2 aa2 = ((const float2*)(st_l + 2 * N))[tid];
      float2 bb2 = ((const float2*)(st_l + 3 * N))[tid];
      float2 pp2 = ((const float2*)(st_l + 4 * N))[tid];
      float2 tf2 = ((const float2*)(tf + l * N))[tid];
      float2 td2 = ((const float2*)(td + l * N))[tid];
      float2 rab2, naa2, nbb2, npp2;
      wkv1(k2.x, v2.x, r2.x, aa2.x, bb2.x, pp2.x, tf2.x, td2.x, rab2.x, naa2.x, nbb2.x, npp2.x);
      wkv1(k2.y, v2.y, r2.y, aa2.y, bb2.y, pp2.y, tf2.y, td2.y, rab2.y, naa2.y, nbb2.y, npp2.y);
      ((float2*)s_buf)[tid] = rab2;
      if (blk == 0) {
        ((float2*)(sto + 2 * N))[tid] = naa2;
        ((float2*)(sto + 3 * N))[tid] = nbb2;
        ((float2*)(sto + 4 * N))[tid] = npp2;
      }
      __syncthreads();
      int row = blk * 4 + (wid >> 1), half = wid & 1;
      float p = wave_pdot(ow_l + (size_t)row * N + half * 512,
                          s_buf + half * 512, 512, lane);
      if (lane == 0) s_part[wid] = p;
      __syncthreads();
      if (tid < 4) {
        int r = blk * 4 + tid;
        sxbuf[r] = xg[r] + s_part[2 * tid] + s_part[2 * tid + 1];
      }
    }
    grid.sync();

    // ======== Stage C: x2 = LN(sx); ffn_k (4096 rows) + ffn_r (1024 rows) ========
    {
      float2 sxv = ((const float2*)sxbuf)[tid];
      float2 x2 = block_ln2(sxv, ln2w + l * N, ln2b + l * N, s_red);
      if (blk == 0) ((float2*)sto)[tid] = x2;
      float2 s0v = ((const float2*)st_l)[tid];
      ((float2*)(s_buf + 0))[tid]    = mix2(x2, s0v, ((const float2*)(fmk + l * N))[tid]);
      ((float2*)(s_buf + 1024))[tid] = mix2(x2, s0v, ((const float2*)(fmr + l * N))[tid]);
      __syncthreads();
      for (int h = wid; h < 40; h += 8) {
        int i = h >> 1, half = h & 1;
        float p;
        if (i < 16) {
          int row = blk * 16 + i;
          p = wave_pdot(fkw_l + (size_t)row * N + half * 512,
                        s_buf + half * 512, 512, lane);
        } else {
          int rr = blk * 4 + (i - 16);
          p = wave_pdot(frw_l + (size_t)rr * N + half * 512,
                        s_buf + 1024 + half * 512, 512, lane);
        }
        if (lane == 0) s_part[h] = p;
      }
      __syncthreads();
      if (tid < 20) {
        float val = s_part[2 * tid] + s_part[2 * tid + 1];
        if (tid < 16) {
          int row = blk * 16 + tid;
          float t = fmaxf(val, 0.f);
          kkbuf[row] = t * t;
        } else {
          int rr = blk * 4 + (tid - 16);
          r2buf[rr] = sigmoidf(val);
        }
      }
    }
    grid.sync();

    // ======== Stage D: x = sx + r2 * (fvw @ kk) (1024 rows × 4096) ========
    {
      ((float4*)s_buf)[tid] = ((const float4*)kkbuf)[tid];
      ((float4*)s_buf)[512 + tid] = ((const float4*)kkbuf)[512 + tid];
      __syncthreads();
      int row = blk * 4 + (wid >> 1), half = wid & 1;
      float p = wave_pdot(fvw_l + (size_t)row * F + half * 2048,
                          s_buf + half * 2048, 2048, lane);
      if (lane == 0) s_part[wid] = p;
      __syncthreads();
      if (tid < 4) {
        int r = blk * 4 + tid;
        xg[r] = sxbuf[r] + r2buf[r] * (s_part[2 * tid] + s_part[2 * tid + 1]);
      }
    }
    grid.sync();
  }

  // ---- head: logits = head @ LN(x) (50277 rows) ----
  {
    float2 xv = ((const float2*)xg)[tid];
    float2 y = block_ln2(xv, lnoutw, lnoutb, s_red);
    ((float2*)s_buf)[tid] = y;
    __syncthreads();
    int gw = blk * 8 + wid;
    for (int row = gw; row < VOCAB; row += GRID * 8) {
      float acc = wave_pdot(head + (size_t)row * N, s_buf, N, lane);
      if (lane == 0) logits[row] = acc;
    }
  }
}

extern "C" void kernel_launch(void* const* d_in, const int* in_sizes, int n_in,
                              void* d_out, int out_size, void* d_ws, size_t ws_size,
                              hipStream_t stream) {
  const int* ctx = (const int*)d_in[0];
  const float* state = (const float*)d_in[1];
  const float* emb = (const float*)d_in[2];
  const float* ln0w = (const float*)d_in[3];
  const float* ln0b = (const float*)d_in[4];
  const float* ln1w = (const float*)d_in[5];
  const float* ln1b = (const float*)d_in[6];
  const float* amk = (const float*)d_in[7];
  const float* amv = (const float*)d_in[8];
  const float* amr = (const float*)d_in[9];
  const float* tf = (const float*)d_in[10];
  const float* td = (const float*)d_in[11];
  const float* kw = (const float*)d_in[12];
  const float* vw = (const float*)d_in[13];
  const float* rw = (const float*)d_in[14];
  const float* ow = (const float*)d_in[15];
  const float* ln2w = (const float*)d_in[16];
  const float* ln2b = (const float*)d_in[17];
  const float* fmk = (const float*)d_in[18];
  const float* fmr = (const float*)d_in[19];
  const float* fkw = (const float*)d_in[20];
  const float* fvw = (const float*)d_in[21];
  const float* frw = (const float*)d_in[22];
  const float* lnoutw = (const float*)d_in[23];
  const float* lnoutb = (const float*)d_in[24];
  const float* head = (const float*)d_in[25];
  float* out = (float*)d_out;
  float* ws = (float*)d_ws;

  void* args[] = {&ctx, &state, &emb, &ln0w, &ln0b, &ln1w, &ln1b,
                  &amk, &amv, &amr, &tf, &td, &kw, &vw, &rw, &ow,
                  &ln2w, &ln2b, &fmk, &fmr, &fkw, &fvw, &frw,
                  &lnoutw, &lnoutb, &head, &out, &ws};
  hipLaunchCooperativeKernel((const void*)k_rwkv, dim3(GRID), dim3(BLOCK),
                             args, 0, stream);
}

// Round 3
// 1150.247 us; speedup vs baseline: 2.7761x; 2.7761x over previous
//
#include <hip/hip_runtime.h>
#include <math.h>

#define N 1024
#define F 4096
#define NLAYERS 24
#define VOCAB 50277
#define GRID 256
#define BLOCK 512   // 8 waves/block, 1 block per CU

__device__ __forceinline__ float wred(float v) {
#pragma unroll
  for (int o = 32; o > 0; o >>= 1) v += __shfl_down(v, o, 64);
  return v;
}

__device__ __forceinline__ float sigmoidf(float x) { return 1.f / (1.f + expf(-x)); }

// coherent (agent-scope, L2-bypassing) scalar load/store for cross-block data
__device__ __forceinline__ float ld_c(const float* p) {
  return __hip_atomic_load(p, __ATOMIC_RELAXED, __HIP_MEMORY_SCOPE_AGENT);
}
__device__ __forceinline__ void st_c(float* p, float v) {
  __hip_atomic_store(p, v, __ATOMIC_RELAXED, __HIP_MEMORY_SCOPE_AGENT);
}

// lightweight grid barrier: relaxed agent atomics, no L2 flush.
// Data visibility: all cross-block data uses ld_c/st_c (coherent point), and
// __syncthreads() drains vmcnt so those stores are complete before arrive.
__device__ __forceinline__ void gbar(unsigned int* cnt, unsigned int* gen) {
  __syncthreads();
  if (threadIdx.x == 0) {
    unsigned int t =
        __hip_atomic_fetch_add(cnt, 1u, __ATOMIC_RELAXED, __HIP_MEMORY_SCOPE_AGENT);
    unsigned int target = t / GRID + 1u;
    if (t % GRID == GRID - 1u) {
      __hip_atomic_store(gen, target, __ATOMIC_RELAXED, __HIP_MEMORY_SCOPE_AGENT);
    } else {
      while (__hip_atomic_load(gen, __ATOMIC_RELAXED, __HIP_MEMORY_SCOPE_AGENT) < target)
        __builtin_amdgcn_s_sleep(4);
    }
  }
  __syncthreads();
}

// partial dot: one wave over `cols` columns (cols multiple of 256)
__device__ __forceinline__ float wave_pdot(const float* __restrict__ wrow,
                                           const float* __restrict__ vec,
                                           int cols, int lane) {
  float acc = 0.f;
  for (int c = lane * 4; c < cols; c += 256) {
    float4 wv = *(const float4*)(wrow + c);
    float4 vv = *(const float4*)(vec + c);
    acc = fmaf(wv.x, vv.x, fmaf(wv.y, vv.y, fmaf(wv.z, vv.z, fmaf(wv.w, vv.w, acc))));
  }
  return wred(acc);
}

__device__ __forceinline__ float2 block_ln2(float2 xv, const float* __restrict__ w,
                                            const float* __restrict__ b, float* s_red) {
  int tid = threadIdx.x;
  __syncthreads();  // protect s_red reuse across calls
  float s = xv.x + xv.y;
  float sq = xv.x * xv.x + xv.y * xv.y;
#pragma unroll
  for (int o = 32; o > 0; o >>= 1) {
    s += __shfl_down(s, o, 64);
    sq += __shfl_down(sq, o, 64);
  }
  int wid = tid >> 6;
  if ((tid & 63) == 0) { s_red[wid] = s; s_red[8 + wid] = sq; }
  __syncthreads();
  if (tid == 0) {
    float ts = 0.f, tq = 0.f;
#pragma unroll
    for (int i = 0; i < 8; i++) { ts += s_red[i]; tq += s_red[8 + i]; }
    float mu = ts * (1.0f / N);
    float var = tq * (1.0f / N) - mu * mu;
    s_red[0] = mu;
    s_red[1] = rsqrtf(var + 1e-5f);
  }
  __syncthreads();
  float mu = s_red[0], rstd = s_red[1];
  float2 wv = ((const float2*)w)[tid];
  float2 bv = ((const float2*)b)[tid];
  float2 y;
  y.x = (xv.x - mu) * rstd * wv.x + bv.x;
  y.y = (xv.y - mu) * rstd * wv.y + bv.y;
  return y;
}

__device__ __forceinline__ float2 mix2(float2 a, float2 s, float2 m) {
  float2 r;
  r.x = a.x * m.x + s.x * (1.f - m.x);
  r.y = a.y * m.y + s.y * (1.f - m.y);
  return r;
}

__device__ __forceinline__ void wkv1(float k, float v, float r, float aa, float bb,
                                     float pp, float tf, float td, float& rab,
                                     float& naa, float& nbb, float& npp) {
  float ww = tf + k;
  float q = fmaxf(pp, ww);
  float e1 = expf(pp - q);
  float e2 = expf(ww - q);
  float a = e1 * aa + e2 * v;
  float b = e1 * bb + e2;
  rab = r * a / b;
  float ww2 = pp + td;
  float q2 = fmaxf(ww2, k);
  float f1 = expf(ww2 - q2);
  float f2 = expf(k - q2);
  naa = f1 * aa + f2 * v;
  nbb = f1 * bb + f2;
  npp = q2;
}

__device__ __forceinline__ float dot4(float4 a, float4 b) {
  return fmaf(a.x, b.x, fmaf(a.y, b.y, fmaf(a.z, b.z, a.w * b.w)));
}

__global__ __launch_bounds__(BLOCK, 1) void k_rwkv(
    const int* __restrict__ ctx, const float* __restrict__ state,
    const float* __restrict__ emb, const float* __restrict__ ln0w,
    const float* __restrict__ ln0b, const float* __restrict__ ln1w,
    const float* __restrict__ ln1b, const float* __restrict__ amk,
    const float* __restrict__ amv, const float* __restrict__ amr,
    const float* __restrict__ tf, const float* __restrict__ td,
    const float* __restrict__ kw, const float* __restrict__ vw,
    const float* __restrict__ rw, const float* __restrict__ ow,
    const float* __restrict__ ln2w, const float* __restrict__ ln2b,
    const float* __restrict__ fmk, const float* __restrict__ fmr,
    const float* __restrict__ fkw, const float* __restrict__ fvw,
    const float* __restrict__ frw, const float* __restrict__ lnoutw,
    const float* __restrict__ lnoutb, const float* __restrict__ head,
    float* __restrict__ out, float* __restrict__ ws, unsigned int* __restrict__ bar) {
  __shared__ __align__(16) float s_x[N];      // layer input x (kept A->B)
  __shared__ __align__(16) float s_buf[3 * N];
  __shared__ __align__(16) float s_kk[16];
  __shared__ float s_part[32];
  __shared__ float s_red[16];

  const int tid = threadIdx.x;
  const int lane = tid & 63;
  const int wid = tid >> 6;
  const int blk = blockIdx.x;

  float* logits = out;
  float* st_out = out + VOCAB;
  float* sxbuf = ws;
  float* kbuf = ws + N;
  float* vbuf = ws + 2 * N;
  float* rbuf = ws + 3 * N;
  float* r2buf = ws + 4 * N;
  float* facc = ws + 5 * N;
  unsigned int* cnt = bar;
  unsigned int* gen = bar + 1;

  for (int l = 0; l < NLAYERS; ++l) {
    const size_t nn = (size_t)N * N;
    const float* st_l = state + (size_t)l * 5 * N;
    float* sto = st_out + (size_t)l * 5 * N;
    const float* kw_l = kw + l * nn;
    const float* vw_l = vw + l * nn;
    const float* rw_l = rw + l * nn;
    const float* ow_l = ow + l * nn;
    const float* fkw_l = fkw + (size_t)l * F * N;
    const float* fvw_l = fvw + (size_t)l * N * F;
    const float* frw_l = frw + l * nn;

    // ================= Stage A: x, LN1, mix, k/v/r GEMVs =================
    {
      float2 xv;
      if (l == 0) {
        int t1 = ctx[1], t0 = ctx[0];
        float2 e1 = ((const float2*)(emb + (size_t)t1 * N))[tid];
        float2 e0 = ((const float2*)(emb + (size_t)t0 * N))[tid];
        float2 rawx;
        rawx.x = (e1.x * 4.f + e0.x) * 0.2f;
        rawx.y = (e1.y * 4.f + e0.y) * 0.2f;
        xv = block_ln2(rawx, ln0w, ln0b, s_red);
      } else {
        int i0 = 2 * tid;
        xv.x = ld_c(sxbuf + i0) + ld_c(r2buf + i0) * ld_c(facc + i0);
        xv.y = ld_c(sxbuf + i0 + 1) + ld_c(r2buf + i0 + 1) * ld_c(facc + i0 + 1);
      }
      ((float2*)s_x)[tid] = xv;
      float2 xl = block_ln2(xv, ln1w + l * N, ln1b + l * N, s_red);
      if (blk == 0) ((float2*)(sto + N))[tid] = xl;
      float2 sv = ((const float2*)(st_l + N))[tid];
      ((float2*)(s_buf))[tid] = mix2(xl, sv, ((const float2*)(amk + l * N))[tid]);
      ((float2*)(s_buf + N))[tid] = mix2(xl, sv, ((const float2*)(amv + l * N))[tid]);
      ((float2*)(s_buf + 2 * N))[tid] = mix2(xl, sv, ((const float2*)(amr + l * N))[tid]);
      __syncthreads();
#pragma unroll
      for (int j = 0; j < 3; ++j) {
        int h = wid + j * 8;               // 24 half-rows
        int i = h >> 1, half = h & 1;
        int m = i >> 2, rr = (blk << 2) + (i & 3);
        const float* wm = (m == 0 ? kw_l : (m == 1 ? vw_l : rw_l));
        float p = wave_pdot(wm + (size_t)rr * N + half * 512,
                            s_buf + m * N + half * 512, 512, lane);
        if (lane == 0) s_part[h] = p;
      }
      __syncthreads();
      if (tid < 12) {
        int m = tid >> 2, rr = (blk << 2) + (tid & 3);
        float val = s_part[2 * tid] + s_part[2 * tid + 1];
        if (m == 0) st_c(kbuf + rr, val);
        else if (m == 1) st_c(vbuf + rr, val);
        else st_c(rbuf + rr, sigmoidf(val));
      }
    }
    gbar(cnt, gen);

    // ================= Stage B: WKV (redundant) + ow GEMV =================
    {
      int i0 = 2 * tid;
      float kx0 = ld_c(kbuf + i0), kx1 = ld_c(kbuf + i0 + 1);
      float vx0 = ld_c(vbuf + i0), vx1 = ld_c(vbuf + i0 + 1);
      float rx0 = ld_c(rbuf + i0), rx1 = ld_c(rbuf + i0 + 1);
      float2 aa2 = ((const float2*)(st_l + 2 * N))[tid];
      float2 bb2 = ((const float2*)(st_l + 3 * N))[tid];
      float2 pp2 = ((const float2*)(st_l + 4 * N))[tid];
      float2 tf2 = ((const float2*)(tf + l * N))[tid];
      float2 td2 = ((const float2*)(td + l * N))[tid];
      float2 rab2, naa2, nbb2, npp2;
      wkv1(kx0, vx0, rx0, aa2.x, bb2.x, pp2.x, tf2.x, td2.x, rab2.x, naa2.x, nbb2.x, npp2.x);
      wkv1(kx1, vx1, rx1, aa2.y, bb2.y, pp2.y, tf2.y, td2.y, rab2.y, naa2.y, nbb2.y, npp2.y);
      ((float2*)s_buf)[tid] = rab2;
      if (blk == 0) {
        ((float2*)(sto + 2 * N))[tid] = naa2;
        ((float2*)(sto + 3 * N))[tid] = nbb2;
        ((float2*)(sto + 4 * N))[tid] = npp2;
      }
      if (tid < 4) st_c(facc + (blk << 2) + tid, 0.f);  // zero for Stage C adds
      __syncthreads();
      int row = (blk << 2) + (wid >> 1), half = wid & 1;
      float p = wave_pdot(ow_l + (size_t)row * N + half * 512,
                          s_buf + half * 512, 512, lane);
      if (lane == 0) s_part[wid] = p;
      __syncthreads();
      if (tid < 4) {
        int r = (blk << 2) + tid;
        st_c(sxbuf + r, s_x[r] + s_part[2 * tid] + s_part[2 * tid + 1]);
      }
    }
    gbar(cnt, gen);

    // ====== Stage C: LN2, mix, ffn_k rows -> relu^2 -> fvw col-panel; ffn_r ======
    {
      int i0 = 2 * tid;
      float2 sxv;
      sxv.x = ld_c(sxbuf + i0);
      sxv.y = ld_c(sxbuf + i0 + 1);
      float2 x2 = block_ln2(sxv, ln2w + l * N, ln2b + l * N, s_red);
      if (blk == 0) ((float2*)sto)[tid] = x2;
      float2 s0v = ((const float2*)st_l)[tid];
      ((float2*)s_buf)[tid] = mix2(x2, s0v, ((const float2*)(fmk + l * N))[tid]);
      ((float2*)(s_buf + N))[tid] = mix2(x2, s0v, ((const float2*)(fmr + l * N))[tid]);
      __syncthreads();
#pragma unroll
      for (int j = 0; j < 2; ++j) {
        int i = wid + 8 * j;               // 16 fkw rows
        int fr = (blk << 4) + i;
        float p = wave_pdot(fkw_l + (size_t)fr * N, s_buf, N, lane);
        if (lane == 0) {
          float t = fmaxf(p, 0.f);
          s_kk[i] = t * t;
        }
      }
      {
        int rr = (blk << 2) + (wid >> 1), half = wid & 1;
        float p = wave_pdot(frw_l + (size_t)rr * N + half * 512,
                            s_buf + N + half * 512, 512, lane);
        if (lane == 0) s_part[wid] = p;
      }
      __syncthreads();
      if (tid < 4)
        st_c(r2buf + (blk << 2) + tid, sigmoidf(s_part[2 * tid] + s_part[2 * tid + 1]));
      // fvw column panel [16*blk, 16*blk+16): perfectly 64B-contiguous per row
      float4 kk0 = ((const float4*)s_kk)[0];
      float4 kk1 = ((const float4*)s_kk)[1];
      float4 kk2 = ((const float4*)s_kk)[2];
      float4 kk3 = ((const float4*)s_kk)[3];
      const float* fv = fvw_l + (blk << 4);
#pragma unroll
      for (int j = 0; j < 2; ++j) {
        int r = (tid + (blk << 2) + j * 512) & (N - 1);  // rotation vs. contention
        const float4* p4 = (const float4*)(fv + (size_t)r * F);
        float4 a0 = p4[0], a1 = p4[1], a2 = p4[2], a3 = p4[3];
        float d = dot4(a0, kk0) + dot4(a1, kk1) + dot4(a2, kk2) + dot4(a3, kk3);
        unsafeAtomicAdd(facc + r, d);
      }
    }
    gbar(cnt, gen);
  }

  // ================= head: logits = head @ LN(x_final) =================
  {
    int i0 = 2 * tid;
    float2 xv;
    xv.x = ld_c(sxbuf + i0) + ld_c(r2buf + i0) * ld_c(facc + i0);
    xv.y = ld_c(sxbuf + i0 + 1) + ld_c(r2buf + i0 + 1) * ld_c(facc + i0 + 1);
    float2 y = block_ln2(xv, lnoutw, lnoutb, s_red);
    ((float2*)s_buf)[tid] = y;
    __syncthreads();
    for (int row = blk * 8 + wid; row < VOCAB; row += GRID * 8) {
      float acc = wave_pdot(head + (size_t)row * N, s_buf, N, lane);
      if (lane == 0) logits[row] = acc;
    }
  }
}

extern "C" void kernel_launch(void* const* d_in, const int* in_sizes, int n_in,
                              void* d_out, int out_size, void* d_ws, size_t ws_size,
                              hipStream_t stream) {
  const int* ctx = (const int*)d_in[0];
  const float* state = (const float*)d_in[1];
  const float* emb = (const float*)d_in[2];
  const float* ln0w = (const float*)d_in[3];
  const float* ln0b = (const float*)d_in[4];
  const float* ln1w = (const float*)d_in[5];
  const float* ln1b = (const float*)d_in[6];
  const float* amk = (const float*)d_in[7];
  const float* amv = (const float*)d_in[8];
  const float* amr = (const float*)d_in[9];
  const float* tf = (const float*)d_in[10];
  const float* td = (const float*)d_in[11];
  const float* kw = (const float*)d_in[12];
  const float* vw = (const float*)d_in[13];
  const float* rw = (const float*)d_in[14];
  const float* ow = (const float*)d_in[15];
  const float* ln2w = (const float*)d_in[16];
  const float* ln2b = (const float*)d_in[17];
  const float* fmk = (const float*)d_in[18];
  const float* fmr = (const float*)d_in[19];
  const float* fkw = (const float*)d_in[20];
  const float* fvw = (const float*)d_in[21];
  const float* frw = (const float*)d_in[22];
  const float* lnoutw = (const float*)d_in[23];
  const float* lnoutb = (const float*)d_in[24];
  const float* head = (const float*)d_in[25];
  float* out = (float*)d_out;
  float* ws = (float*)d_ws;
  unsigned int* bar = (unsigned int*)((char*)d_ws + 32768);

  hipMemsetAsync(bar, 0, 2 * sizeof(unsigned int), stream);

  void* args[] = {&ctx, &state, &emb, &ln0w, &ln0b, &ln1w, &ln1b,
                  &amk, &amv, &amr, &tf, &td, &kw, &vw, &rw, &ow,
                  &ln2w, &ln2b, &fmk, &fmr, &fkw, &fvw, &frw,
                  &lnoutw, &lnoutb, &head, &out, &ws, &bar};
  hipLaunchCooperativeKernel((const void*)k_rwkv, dim3(GRID), dim3(BLOCK),
                             args, 0, stream);
}

// Round 4
// 830.572 us; speedup vs baseline: 3.8446x; 1.3849x over previous
//
#include <hip/hip_runtime.h>
#include <math.h>

#define N 1024
#define F 4096
#define NLAYERS 24
#define VOCAB 50277
#define GRID 256
#define BLOCK 512   // 8 waves/block, 1 block per CU

// barrier region layout (in ws, at byte offset 32768):
//   arrive[256] flags, stride 16 dwords (one 64B line each)  -> 16 KB
//   release[32] copies, stride 16 dwords                     -> 2 KB
#define BAR_OFF_BYTES 32768
#define ARRIVE_STRIDE 16
#define RELEASE_OFF (256 * ARRIVE_STRIDE)
#define BAR_DWORDS (256 * ARRIVE_STRIDE + 32 * ARRIVE_STRIDE)

__device__ __forceinline__ float wred(float v) {
#pragma unroll
  for (int o = 32; o > 0; o >>= 1) v += __shfl_down(v, o, 64);
  return v;
}

__device__ __forceinline__ float sigmoidf(float x) { return 1.f / (1.f + expf(-x)); }

// coherent (agent-scope, L2-bypassing) scalar load/store for cross-block data
__device__ __forceinline__ float ld_c(const float* p) {
  return __hip_atomic_load(p, __ATOMIC_RELAXED, __HIP_MEMORY_SCOPE_AGENT);
}
__device__ __forceinline__ void st_c(float* p, float v) {
  __hip_atomic_store(p, v, __ATOMIC_RELAXED, __HIP_MEMORY_SCOPE_AGENT);
}
__device__ __forceinline__ unsigned ld_cu(const unsigned* p) {
  return __hip_atomic_load(p, __ATOMIC_RELAXED, __HIP_MEMORY_SCOPE_AGENT);
}
__device__ __forceinline__ void st_cu(unsigned* p, unsigned v) {
  __hip_atomic_store(p, v, __ATOMIC_RELAXED, __HIP_MEMORY_SCOPE_AGENT);
}

// Grid barrier v2: per-block arrival flags (separate cache lines, no RMW),
// master block sweeps flags in parallel (wave 0, 4 flags/lane), release is
// broadcast to 32 spread copies to avoid poll hot-spotting.
// Data visibility: cross-block data uses agent-scope (coherent-point) ops and
// __syncthreads() drains vmcnt before the arrive flag store.
__device__ __forceinline__ void gbar(unsigned* bar, unsigned gen, int blk, int tid) {
  unsigned* arrive = bar;
  unsigned* release = bar + RELEASE_OFF;
  __syncthreads();
  if (tid == 0) st_cu(arrive + blk * ARRIVE_STRIDE, gen);
  if (blk == 0) {
    if (tid < 64) {
      for (;;) {
        bool ok = true;
#pragma unroll
        for (int i = 0; i < 4; ++i) {
          unsigned v = ld_cu(arrive + (tid * 4 + i) * ARRIVE_STRIDE);
          ok &= (v >= gen);
        }
        if (__all(ok)) break;
        __builtin_amdgcn_s_sleep(2);
      }
      if (tid < 32) st_cu(release + tid * ARRIVE_STRIDE, gen);
    }
  } else if (tid == 0) {
    const unsigned* rel = release + (blk & 31) * ARRIVE_STRIDE;
    while (ld_cu(rel) < gen) __builtin_amdgcn_s_sleep(2);
  }
  __syncthreads();
}

// partial dot: one wave over `cols` columns (cols multiple of 256)
__device__ __forceinline__ float wave_pdot(const float* __restrict__ wrow,
                                           const float* __restrict__ vec,
                                           int cols, int lane) {
  float acc = 0.f;
  for (int c = lane * 4; c < cols; c += 256) {
    float4 wv = *(const float4*)(wrow + c);
    float4 vv = *(const float4*)(vec + c);
    acc = fmaf(wv.x, vv.x, fmaf(wv.y, vv.y, fmaf(wv.z, vv.z, fmaf(wv.w, vv.w, acc))));
  }
  return wred(acc);
}

__device__ __forceinline__ float2 block_ln2(float2 xv, const float* __restrict__ w,
                                            const float* __restrict__ b, float* s_red) {
  int tid = threadIdx.x;
  __syncthreads();  // protect s_red reuse across calls
  float s = xv.x + xv.y;
  float sq = xv.x * xv.x + xv.y * xv.y;
#pragma unroll
  for (int o = 32; o > 0; o >>= 1) {
    s += __shfl_down(s, o, 64);
    sq += __shfl_down(sq, o, 64);
  }
  int wid = tid >> 6;
  if ((tid & 63) == 0) { s_red[wid] = s; s_red[8 + wid] = sq; }
  __syncthreads();
  if (tid == 0) {
    float ts = 0.f, tq = 0.f;
#pragma unroll
    for (int i = 0; i < 8; i++) { ts += s_red[i]; tq += s_red[8 + i]; }
    float mu = ts * (1.0f / N);
    float var = tq * (1.0f / N) - mu * mu;
    s_red[0] = mu;
    s_red[1] = rsqrtf(var + 1e-5f);
  }
  __syncthreads();
  float mu = s_red[0], rstd = s_red[1];
  float2 wv = ((const float2*)w)[tid];
  float2 bv = ((const float2*)b)[tid];
  float2 y;
  y.x = (xv.x - mu) * rstd * wv.x + bv.x;
  y.y = (xv.y - mu) * rstd * wv.y + bv.y;
  return y;
}

__device__ __forceinline__ float2 mix2(float2 a, float2 s, float2 m) {
  float2 r;
  r.x = a.x * m.x + s.x * (1.f - m.x);
  r.y = a.y * m.y + s.y * (1.f - m.y);
  return r;
}

__device__ __forceinline__ void wkv1(float k, float v, float r, float aa, float bb,
                                     float pp, float tf, float td, float& rab,
                                     float& naa, float& nbb, float& npp) {
  float ww = tf + k;
  float q = fmaxf(pp, ww);
  float e1 = expf(pp - q);
  float e2 = expf(ww - q);
  float a = e1 * aa + e2 * v;
  float b = e1 * bb + e2;
  rab = r * a / b;
  float ww2 = pp + td;
  float q2 = fmaxf(ww2, k);
  float f1 = expf(ww2 - q2);
  float f2 = expf(k - q2);
  naa = f1 * aa + f2 * v;
  nbb = f1 * bb + f2;
  npp = q2;
}

__device__ __forceinline__ float dot4(float4 a, float4 b) {
  return fmaf(a.x, b.x, fmaf(a.y, b.y, fmaf(a.z, b.z, a.w * b.w)));
}

__global__ __launch_bounds__(BLOCK, 1) void k_rwkv(
    const int* __restrict__ ctx, const float* __restrict__ state,
    const float* __restrict__ emb, const float* __restrict__ ln0w,
    const float* __restrict__ ln0b, const float* __restrict__ ln1w,
    const float* __restrict__ ln1b, const float* __restrict__ amk,
    const float* __restrict__ amv, const float* __restrict__ amr,
    const float* __restrict__ tf, const float* __restrict__ td,
    const float* __restrict__ kw, const float* __restrict__ vw,
    const float* __restrict__ rw, const float* __restrict__ ow,
    const float* __restrict__ ln2w, const float* __restrict__ ln2b,
    const float* __restrict__ fmk, const float* __restrict__ fmr,
    const float* __restrict__ fkw, const float* __restrict__ fvw,
    const float* __restrict__ frw, const float* __restrict__ lnoutw,
    const float* __restrict__ lnoutb, const float* __restrict__ head,
    float* __restrict__ out, float* __restrict__ ws, unsigned int* __restrict__ bar) {
  __shared__ __align__(16) float s_x[N];      // layer input x (kept A->B)
  __shared__ __align__(16) float s_buf[3 * N];
  __shared__ __align__(16) float s_kk[16];
  __shared__ float s_part[32];
  __shared__ float s_red[16];

  const int tid = threadIdx.x;
  const int lane = tid & 63;
  const int wid = tid >> 6;
  const int blk = blockIdx.x;

  float* logits = out;
  float* st_out = out + VOCAB;
  float* sxbuf = ws;
  float* kbuf = ws + N;
  float* vbuf = ws + 2 * N;
  float* rbuf = ws + 3 * N;
  float* r2buf = ws + 4 * N;
  float* facc = ws + 5 * N;
  unsigned genc = 0;

  for (int l = 0; l < NLAYERS; ++l) {
    const size_t nn = (size_t)N * N;
    const float* st_l = state + (size_t)l * 5 * N;
    float* sto = st_out + (size_t)l * 5 * N;
    const float* kw_l = kw + l * nn;
    const float* vw_l = vw + l * nn;
    const float* rw_l = rw + l * nn;
    const float* ow_l = ow + l * nn;
    const float* fkw_l = fkw + (size_t)l * F * N;
    const float* fvw_l = fvw + (size_t)l * N * F;
    const float* frw_l = frw + l * nn;

    // ================= Stage A: x, LN1, mix, k/v/r GEMVs =================
    {
      float2 xv;
      if (l == 0) {
        int t1 = ctx[1], t0 = ctx[0];
        float2 e1 = ((const float2*)(emb + (size_t)t1 * N))[tid];
        float2 e0 = ((const float2*)(emb + (size_t)t0 * N))[tid];
        float2 rawx;
        rawx.x = (e1.x * 4.f + e0.x) * 0.2f;
        rawx.y = (e1.y * 4.f + e0.y) * 0.2f;
        xv = block_ln2(rawx, ln0w, ln0b, s_red);
      } else {
        int i0 = 2 * tid;
        xv.x = ld_c(sxbuf + i0) + ld_c(r2buf + i0) * ld_c(facc + i0);
        xv.y = ld_c(sxbuf + i0 + 1) + ld_c(r2buf + i0 + 1) * ld_c(facc + i0 + 1);
      }
      ((float2*)s_x)[tid] = xv;
      float2 xl = block_ln2(xv, ln1w + l * N, ln1b + l * N, s_red);
      if (blk == 0) ((float2*)(sto + N))[tid] = xl;
      float2 sv = ((const float2*)(st_l + N))[tid];
      ((float2*)(s_buf))[tid] = mix2(xl, sv, ((const float2*)(amk + l * N))[tid]);
      ((float2*)(s_buf + N))[tid] = mix2(xl, sv, ((const float2*)(amv + l * N))[tid]);
      ((float2*)(s_buf + 2 * N))[tid] = mix2(xl, sv, ((const float2*)(amr + l * N))[tid]);
      __syncthreads();
#pragma unroll
      for (int j = 0; j < 3; ++j) {
        int h = wid + j * 8;               // 24 half-rows
        int i = h >> 1, half = h & 1;
        int m = i >> 2, rr = (blk << 2) + (i & 3);
        const float* wm = (m == 0 ? kw_l : (m == 1 ? vw_l : rw_l));
        float p = wave_pdot(wm + (size_t)rr * N + half * 512,
                            s_buf + m * N + half * 512, 512, lane);
        if (lane == 0) s_part[h] = p;
      }
      __syncthreads();
      if (tid < 12) {
        int m = tid >> 2, rr = (blk << 2) + (tid & 3);
        float val = s_part[2 * tid] + s_part[2 * tid + 1];
        if (m == 0) st_c(kbuf + rr, val);
        else if (m == 1) st_c(vbuf + rr, val);
        else st_c(rbuf + rr, sigmoidf(val));
      }
    }
    gbar(bar, ++genc, blk, tid);

    // ================= Stage B: WKV (redundant) + ow GEMV =================
    {
      int i0 = 2 * tid;
      float kx0 = ld_c(kbuf + i0), kx1 = ld_c(kbuf + i0 + 1);
      float vx0 = ld_c(vbuf + i0), vx1 = ld_c(vbuf + i0 + 1);
      float rx0 = ld_c(rbuf + i0), rx1 = ld_c(rbuf + i0 + 1);
      float2 aa2 = ((const float2*)(st_l + 2 * N))[tid];
      float2 bb2 = ((const float2*)(st_l + 3 * N))[tid];
      float2 pp2 = ((const float2*)(st_l + 4 * N))[tid];
      float2 tf2 = ((const float2*)(tf + l * N))[tid];
      float2 td2 = ((const float2*)(td + l * N))[tid];
      float2 rab2, naa2, nbb2, npp2;
      wkv1(kx0, vx0, rx0, aa2.x, bb2.x, pp2.x, tf2.x, td2.x, rab2.x, naa2.x, nbb2.x, npp2.x);
      wkv1(kx1, vx1, rx1, aa2.y, bb2.y, pp2.y, tf2.y, td2.y, rab2.y, naa2.y, nbb2.y, npp2.y);
      ((float2*)s_buf)[tid] = rab2;
      if (blk == 0) {
        ((float2*)(sto + 2 * N))[tid] = naa2;
        ((float2*)(sto + 3 * N))[tid] = nbb2;
        ((float2*)(sto + 4 * N))[tid] = npp2;
      }
      if (tid < 4) st_c(facc + (blk << 2) + tid, 0.f);  // zero for Stage C adds
      __syncthreads();
      int row = (blk << 2) + (wid >> 1), half = wid & 1;
      float p = wave_pdot(ow_l + (size_t)row * N + half * 512,
                          s_buf + half * 512, 512, lane);
      if (lane == 0) s_part[wid] = p;
      __syncthreads();
      if (tid < 4) {
        int r = (blk << 2) + tid;
        st_c(sxbuf + r, s_x[r] + s_part[2 * tid] + s_part[2 * tid + 1]);
      }
    }
    gbar(bar, ++genc, blk, tid);

    // ====== Stage C: LN2, mix, ffn_k rows -> relu^2 -> fvw col-panel; ffn_r ======
    {
      int i0 = 2 * tid;
      float2 sxv;
      sxv.x = ld_c(sxbuf + i0);
      sxv.y = ld_c(sxbuf + i0 + 1);
      float2 x2 = block_ln2(sxv, ln2w + l * N, ln2b + l * N, s_red);
      if (blk == 0) ((float2*)sto)[tid] = x2;
      float2 s0v = ((const float2*)st_l)[tid];
      ((float2*)s_buf)[tid] = mix2(x2, s0v, ((const float2*)(fmk + l * N))[tid]);
      ((float2*)(s_buf + N))[tid] = mix2(x2, s0v, ((const float2*)(fmr + l * N))[tid]);
      __syncthreads();
#pragma unroll
      for (int j = 0; j < 2; ++j) {
        int i = wid + 8 * j;               // 16 fkw rows
        int fr = (blk << 4) + i;
        float p = wave_pdot(fkw_l + (size_t)fr * N, s_buf, N, lane);
        if (lane == 0) {
          float t = fmaxf(p, 0.f);
          s_kk[i] = t * t;
        }
      }
      {
        int rr = (blk << 2) + (wid >> 1), half = wid & 1;
        float p = wave_pdot(frw_l + (size_t)rr * N + half * 512,
                            s_buf + N + half * 512, 512, lane);
        if (lane == 0) s_part[wid] = p;
      }
      __syncthreads();
      if (tid < 4)
        st_c(r2buf + (blk << 2) + tid, sigmoidf(s_part[2 * tid] + s_part[2 * tid + 1]));
      // fvw column panel [16*blk, 16*blk+16): perfectly 64B-contiguous per row
      float4 kk0 = ((const float4*)s_kk)[0];
      float4 kk1 = ((const float4*)s_kk)[1];
      float4 kk2 = ((const float4*)s_kk)[2];
      float4 kk3 = ((const float4*)s_kk)[3];
      const float* fv = fvw_l + (blk << 4);
#pragma unroll
      for (int j = 0; j < 2; ++j) {
        int r = (tid + (blk << 2) + j * 512) & (N - 1);  // rotation vs. contention
        const float4* p4 = (const float4*)(fv + (size_t)r * F);
        float4 a0 = p4[0], a1 = p4[1], a2 = p4[2], a3 = p4[3];
        float d = dot4(a0, kk0) + dot4(a1, kk1) + dot4(a2, kk2) + dot4(a3, kk3);
        unsafeAtomicAdd(facc + r, d);
      }
    }
    gbar(bar, ++genc, blk, tid);
  }

  // ================= head: logits = head @ LN(x_final) =================
  {
    int i0 = 2 * tid;
    float2 xv;
    xv.x = ld_c(sxbuf + i0) + ld_c(r2buf + i0) * ld_c(facc + i0);
    xv.y = ld_c(sxbuf + i0 + 1) + ld_c(r2buf + i0 + 1) * ld_c(facc + i0 + 1);
    float2 y = block_ln2(xv, lnoutw, lnoutb, s_red);
    ((float2*)s_buf)[tid] = y;
    __syncthreads();
    for (int row = blk * 8 + wid; row < VOCAB; row += GRID * 8) {
      float acc = wave_pdot(head + (size_t)row * N, s_buf, N, lane);
      if (lane == 0) logits[row] = acc;
    }
  }
}

extern "C" void kernel_launch(void* const* d_in, const int* in_sizes, int n_in,
                              void* d_out, int out_size, void* d_ws, size_t ws_size,
                              hipStream_t stream) {
  const int* ctx = (const int*)d_in[0];
  const float* state = (const float*)d_in[1];
  const float* emb = (const float*)d_in[2];
  const float* ln0w = (const float*)d_in[3];
  const float* ln0b = (const float*)d_in[4];
  const float* ln1w = (const float*)d_in[5];
  const float* ln1b = (const float*)d_in[6];
  const float* amk = (const float*)d_in[7];
  const float* amv = (const float*)d_in[8];
  const float* amr = (const float*)d_in[9];
  const float* tf = (const float*)d_in[10];
  const float* td = (const float*)d_in[11];
  const float* kw = (const float*)d_in[12];
  const float* vw = (const float*)d_in[13];
  const float* rw = (const float*)d_in[14];
  const float* ow = (const float*)d_in[15];
  const float* ln2w = (const float*)d_in[16];
  const float* ln2b = (const float*)d_in[17];
  const float* fmk = (const float*)d_in[18];
  const float* fmr = (const float*)d_in[19];
  const float* fkw = (const float*)d_in[20];
  const float* fvw = (const float*)d_in[21];
  const float* frw = (const float*)d_in[22];
  const float* lnoutw = (const float*)d_in[23];
  const float* lnoutb = (const float*)d_in[24];
  const float* head = (const float*)d_in[25];
  float* out = (float*)d_out;
  float* ws = (float*)d_ws;
  unsigned int* bar = (unsigned int*)((char*)d_ws + BAR_OFF_BYTES);

  hipMemsetAsync(bar, 0, BAR_DWORDS * sizeof(unsigned int), stream);

  void* args[] = {&ctx, &state, &emb, &ln0w, &ln0b, &ln1w, &ln1b,
                  &amk, &amv, &amr, &tf, &td, &kw, &vw, &rw, &ow,
                  &ln2w, &ln2b, &fmk, &fmr, &fkw, &fvw, &frw,
                  &lnoutw, &lnoutb, &head, &out, &ws, &bar};
  hipLaunchCooperativeKernel((const void*)k_rwkv, dim3(GRID), dim3(BLOCK),
                             args, 0, stream);
}